// Round 6
// baseline (125.527 us; speedup 1.0000x reference)
//
#include <hip/hip_runtime.h>
#include <hip/hip_bf16.h>

#define B_ 2
#define T_ 2048
#define C_ 1024
#define NH 16
#define NKV 4
#define HD 64
#define NQKV 1536

typedef __attribute__((ext_vector_type(4))) float f32x4;
typedef __attribute__((ext_vector_type(16))) float f32x16;
typedef __attribute__((ext_vector_type(8))) short bf16x8;

__device__ __forceinline__ unsigned short f2bf(float f) {
  __hip_bfloat16 h = __float2bfloat16(f);
  unsigned short u;
  __builtin_memcpy(&u, &h, 2);
  return u;
}

__device__ __forceinline__ void gload16(const void* g, void* l) {
  __builtin_amdgcn_global_load_lds(
      (const __attribute__((address_space(1))) void*)g,
      (__attribute__((address_space(3))) void*)l, 16, 0, 0);
}

__device__ __forceinline__ unsigned cvtpk(float lo, float hi_) {
  unsigned w;
  asm("v_cvt_pk_bf16_f32 %0, %1, %2" : "=v"(w) : "v"(lo), "v"(hi_));
  return w;
}

__device__ __forceinline__ void swap32(unsigned& x, unsigned& y) {
  asm("v_permlane32_swap_b32 %0, %1" : "+v"(x), "+v"(y));
}

__device__ __forceinline__ bf16x8 mk8(unsigned a, unsigned b, unsigned c, unsigned d) {
  unsigned t[4] = {a, b, c, d};
  bf16x8 r;
  __builtin_memcpy(&r, t, 16);
  return r;
}

// ---------------- fused f32 -> bf16 convert for all 5 tensors (1 launch) ----------------
#define NX4  1048576
#define NW4  262144
#define NK4  65536
#define O1 (NX4)
#define O2 (O1 + NW4)
#define O3 (O2 + NK4)
#define O4 (O3 + NK4)
#define OT (O4 + NW4)

__global__ __launch_bounds__(256) void conv_all(
    const float* __restrict__ x, const float* __restrict__ wq, const float* __restrict__ wk,
    const float* __restrict__ wv, const float* __restrict__ wo,
    unsigned short* __restrict__ xb, unsigned short* __restrict__ wqkvb,
    unsigned short* __restrict__ wob) {
  int i = blockIdx.x * blockDim.x + threadIdx.x;
  const int stride = gridDim.x * blockDim.x;
  for (; i < OT; i += stride) {
    const float* src;
    unsigned short* dst;
    int j;
    if (i < O1)      { src = x;  dst = xb;                    j = i; }
    else if (i < O2) { src = wq; dst = wqkvb;                 j = i - O1; }
    else if (i < O3) { src = wk; dst = wqkvb + 1024 * 1024;   j = i - O2; }
    else if (i < O4) { src = wv; dst = wqkvb + 1280 * 1024;   j = i - O3; }
    else             { src = wo; dst = wob;                   j = i - O4; }
    const float4 v = reinterpret_cast<const float4*>(src)[j];
    ushort4 o;
    o.x = f2bf(v.x); o.y = f2bf(v.y); o.z = f2bf(v.z); o.w = f2bf(v.w);
    reinterpret_cast<ushort4*>(dst)[j] = o;
  }
}

// ---------------- GEMM: C[M,N] = A[M,K] * B[N,K]^T  (bf16 in, f32 out) ----------------
#define BM 128
#define BN 128
#define BK 64

__global__ __launch_bounds__(256) void gemm_bt(const unsigned short* __restrict__ A,
                                               const unsigned short* __restrict__ Bw,
                                               float* __restrict__ C, int M, int N, int K) {
  __shared__ unsigned short Al[BM * BK];
  __shared__ unsigned short Bl[BN * BK];
  const int tid = threadIdx.x;
  const int lane = tid & 63;
  const int wid = tid >> 6;
  const int r = lane & 15, g = lane >> 4;
  const int wm = (wid >> 1) * 64, wn = (wid & 1) * 64;
  const int bm0 = blockIdx.y * BM, bn0 = blockIdx.x * BN;
  const int lrow = lane >> 3;
  const int lcol = ((lane & 7) ^ lrow) * 8;
  const unsigned short* Asrc = A + (size_t)(bm0 + wid * 32 + lrow) * K + lcol;
  const unsigned short* Bsrc = Bw + (size_t)(bn0 + wid * 32 + lrow) * K + lcol;
  const int fsw = (r & 7) << 4;
  const char* Ac = (const char*)Al;
  const char* Bc = (const char*)Bl;
  f32x4 acc[4][4] = {};
  for (int k0 = 0; k0 < K; k0 += BK) {
    __syncthreads();
#pragma unroll
    for (int i = 0; i < 4; ++i) {
      gload16(Asrc + (size_t)(i * 8) * K + k0, Al + (wid * 32 + i * 8) * BK);
      gload16(Bsrc + (size_t)(i * 8) * K + k0, Bl + (wid * 32 + i * 8) * BK);
    }
    __syncthreads();
    bf16x8 af[4][2], bfr[4][2];
#pragma unroll
    for (int mi = 0; mi < 4; ++mi)
#pragma unroll
      for (int s = 0; s < 2; ++s)
        af[mi][s] = *reinterpret_cast<const bf16x8*>(
            Ac + (wm + mi * 16 + r) * 128 + ((s * 64 + g * 16) ^ fsw));
#pragma unroll
    for (int ni = 0; ni < 4; ++ni)
#pragma unroll
      for (int s = 0; s < 2; ++s)
        bfr[ni][s] = *reinterpret_cast<const bf16x8*>(
            Bc + (wn + ni * 16 + r) * 128 + ((s * 64 + g * 16) ^ fsw));
#pragma unroll
    for (int s = 0; s < 2; ++s)
#pragma unroll
      for (int mi = 0; mi < 4; ++mi)
#pragma unroll
        for (int ni = 0; ni < 4; ++ni)
          acc[mi][ni] = __builtin_amdgcn_mfma_f32_16x16x32_bf16(af[mi][s], bfr[ni][s],
                                                                acc[mi][ni], 0, 0, 0);
  }
#pragma unroll
  for (int mi = 0; mi < 4; ++mi)
#pragma unroll
    for (int ni = 0; ni < 4; ++ni) {
      const int row = bm0 + wm + mi * 16 + g * 4;
      const int col = bn0 + wn + ni * 16 + r;
#pragma unroll
      for (int e = 0; e < 4; ++e)
        C[(size_t)(row + e) * N + col] = acc[mi][ni][e];
    }
}

// ---------------- postprocess: rotary + rmsnorm on q,k ; gate+ve on v ----------------
__global__ __launch_bounds__(256) void postproc(
    const float* __restrict__ qkv, const float* __restrict__ x, const float* __restrict__ ve,
    const float* __restrict__ cosb, const float* __restrict__ sinb, const float* __restrict__ Wg,
    unsigned short* __restrict__ Qn, unsigned short* __restrict__ Kn, unsigned short* __restrict__ Vt) {
  const int tok = blockIdx.x;
  const int b = tok / T_, t = tok % T_;
  const int wid = threadIdx.x >> 6, lane = threadIdx.x & 63;
  const float* qrow = qkv + (size_t)tok * NQKV;
  const float c = cosb[t * 32 + (lane & 31)];
  const float s = sinb[t * 32 + (lane & 31)];
  for (int u = wid; u < 24; u += 4) {
    if (u < 20) {
      const int off = (u < 16) ? u * 64 : 1024 + (u - 16) * 64;
      float v0 = qrow[off + lane];
      float p = __shfl_xor(v0, 32);
      float rot = (lane < 32) ? (v0 * c + p * s) : (v0 * c - p * s);
      float sq = rot * rot;
#pragma unroll
      for (int m = 1; m < 64; m <<= 1) sq += __shfl_xor(sq, m);
      float outv = rot * rsqrtf(sq * (1.0f / 64.0f) + 1.1920929e-7f) *
                   ((u < 16) ? 0.21640425613334453f : 1.2f);
      if (u < 16)
        Qn[((size_t)(b * NH + u) * T_ + t) * HD + lane] = f2bf(outv);
      else
        Kn[((size_t)(b * NKV + (u - 16)) * T_ + t) * HD + lane] = f2bf(outv);
    } else {
      const int kv = u - 20;
      float dot = 0.f;
#pragma unroll
      for (int i = 0; i < 12; ++i) dot += x[(size_t)tok * C_ + i] * Wg[kv * 12 + i];
      const float gate = 3.0f / (1.0f + __expf(-dot));
      const float vv = qrow[1280 + kv * 64 + lane] + gate * ve[(size_t)tok * (NKV * HD) + kv * 64 + lane];
      Vt[((size_t)(b * NKV + kv) * HD + lane) * T_ + t] = f2bf(vv);
    }
  }
}

// ---------------- flash attention: 32x32 MFMA, in-register softmax ----------------
// grid (32, NH, B), 128 thr (2 waves). Heavy-first q0. Wave owns 32 queries.
// QK^T swapped: S^T = mfma32(A=K, B=Q) over 4 k-chunks; C-layout row=s=(e&3)+8(e>>2)+4hi,
// col=q=lane&31. Softmax in-register (cross-half via shfl_xor 32). P->PV B-fragment via
// 16 cvt_pk_bf16 + 8 permlane32_swap (chunk pair (m,m+2): x'=from-lo-half, y'=from-hi-half).
// K/V staged by global_load_lds w16 into dbuf LDS, source pre-swizzled col^=(row&7)<<4,
// 2-phase pipeline: stage(i+1); compute(i); barrier.
__global__ __launch_bounds__(128, 2) void attn_fwd(
    const unsigned short* __restrict__ Qn, const unsigned short* __restrict__ Kn,
    const unsigned short* __restrict__ Vt, unsigned short* __restrict__ Y,
    const int* __restrict__ wlp) {
  __shared__ unsigned short Kl[2][64 * 64];   // [s][d] swizzled, 8KB each
  __shared__ unsigned short Vl[2][64 * 64];   // [d][s] swizzled, 8KB each
  const int b = blockIdx.z, h = blockIdx.y;
  const int kvh = h >> 2;
  const int tid = threadIdx.x;
  const int wid = tid >> 6, lane = tid & 63;
  const int l31 = lane & 31, hi = lane >> 5;
  const int q0 = (gridDim.x - 1 - blockIdx.x) * 64;   // heavy-first
  const int qs = q0 + wid * 32;
  const int q = qs + l31;
  const int wl = *wlp;
  const unsigned short* Kb = Kn + (size_t)(b * NKV + kvh) * T_ * HD;
  const unsigned short* Vb = Vt + (size_t)(b * NKV + kvh) * HD * T_;
  bf16x8 qf[4];
  {
    const unsigned short* Qb = Qn + ((size_t)(b * NH + h) * T_ + q) * HD;
#pragma unroll
    for (int kc = 0; kc < 4; ++kc)
      qf[kc] = *reinterpret_cast<const bf16x8*>(Qb + kc * 16 + hi * 8);
  }
  f32x16 oA = {}, oB = {};
  float mrun = -1e30f, lrun = 0.f;
  int slo = q0 - wl; if (slo < 0) slo = 0;
  slo &= ~63;
  const int send = q0 + 63;
  // staging geometry: per gload16, wave covers 8 rows; lane l -> row base+ (l>>3), 16B slot l&7
  const int srow8 = lane >> 3;
  const int scol = ((lane & 7) ^ srow8) * 8;   // pre-swizzled source element col

#define STAGE(SB, BUF)                                                                   \
  {                                                                                      \
    _Pragma("unroll")                                                                    \
    for (int u = 0; u < 4; ++u) {                                                        \
      const int br = wid * 32 + u * 8;                                                   \
      gload16(Kb + (size_t)((SB) + br + srow8) * HD + scol, Kl[BUF] + br * 64);          \
      gload16(Vb + (size_t)(br + srow8) * T_ + (SB) + scol, Vl[BUF] + br * 64);          \
    }                                                                                    \
  }

  STAGE(slo, 0);
  __syncthreads();

  int cur = 0;
  for (int sb = slo; sb <= send; sb += 64) {
    if (sb + 64 <= send) { STAGE(sb + 64, cur ^ 1); }
    if (sb <= qs + 31 && sb + 63 >= qs - wl) {
      const char* Kc = (const char*)Kl[cur];
      const char* Vc = (const char*)Vl[cur];
      // QK^T: two 32x32 S-tiles (s sub-blocks), 4 chained k-chunks each
      f32x16 sA = {}, sB = {};
      const int rA = l31, rB = 32 + l31;
      const int swA = (rA & 7) << 4, swB = (rB & 7) << 4;
#pragma unroll
      for (int kc = 0; kc < 4; ++kc) {
        const bf16x8 kfA = *reinterpret_cast<const bf16x8*>(Kc + rA * 128 + ((kc * 32 + hi * 16) ^ swA));
        sA = __builtin_amdgcn_mfma_f32_32x32x16_bf16(kfA, qf[kc], sA, 0, 0, 0);
        const bf16x8 kfB = *reinterpret_cast<const bf16x8*>(Kc + rB * 128 + ((kc * 32 + hi * 16) ^ swB));
        sB = __builtin_amdgcn_mfma_f32_32x32x16_bf16(kfB, qf[kc], sB, 0, 0, 0);
      }
      // mask on edge tiles only
      if (sb + 63 > qs || sb < qs + 31 - wl) {
#pragma unroll
        for (int e = 0; e < 16; ++e) {
          const int r0 = (e & 3) + 8 * (e >> 2) + 4 * hi;
          const int s0 = sb + r0, s1 = sb + 32 + r0;
          sA[e] = ((unsigned)(q - s0) <= (unsigned)wl) ? sA[e] : -__builtin_inff();
          sB[e] = ((unsigned)(q - s1) <= (unsigned)wl) ? sB[e] : -__builtin_inff();
        }
      }
      float pm = sA[0];
#pragma unroll
      for (int e = 1; e < 16; ++e) pm = fmaxf(pm, sA[e]);
#pragma unroll
      for (int e = 0; e < 16; ++e) pm = fmaxf(pm, sB[e]);
      pm = fmaxf(pm, __shfl_xor(pm, 32));
      if (!__all(pm <= mrun + 8.0f)) {          // defer-max (log2 units)
        const float mnew = fmaxf(mrun, pm);
        const float scl = exp2f(mrun - mnew);
        lrun *= scl;
#pragma unroll
        for (int e = 0; e < 16; ++e) { oA[e] *= scl; oB[e] *= scl; }
        mrun = mnew;
      }
      float ps = 0.f;
      unsigned W0[8], W1[8];
#pragma unroll
      for (int m2 = 0; m2 < 8; ++m2) {
        const float a0 = exp2f(sA[2 * m2] - mrun), a1 = exp2f(sA[2 * m2 + 1] - mrun);
        ps += a0 + a1;
        W0[m2] = cvtpk(a0, a1);
        const float b0 = exp2f(sB[2 * m2] - mrun), b1 = exp2f(sB[2 * m2 + 1] - mrun);
        ps += b0 + b1;
        W1[m2] = cvtpk(b0, b1);
      }
      ps += __shfl_xor(ps, 32);
      lrun += ps;
      // redistribute P into PV B-fragments: pf[ks] holds P^T[s=sb+ks*16+hi*8+j][q]
      bf16x8 pfs[4];
      {
        unsigned x0, x1, y0, y1;
        x0 = W0[0]; y0 = W0[2]; x1 = W0[1]; y1 = W0[3];
        swap32(x0, y0); swap32(x1, y1); pfs[0] = mk8(x0, x1, y0, y1);
        x0 = W0[4]; y0 = W0[6]; x1 = W0[5]; y1 = W0[7];
        swap32(x0, y0); swap32(x1, y1); pfs[1] = mk8(x0, x1, y0, y1);
        x0 = W1[0]; y0 = W1[2]; x1 = W1[1]; y1 = W1[3];
        swap32(x0, y0); swap32(x1, y1); pfs[2] = mk8(x0, x1, y0, y1);
        x0 = W1[4]; y0 = W1[6]; x1 = W1[5]; y1 = W1[7];
        swap32(x0, y0); swap32(x1, y1); pfs[3] = mk8(x0, x1, y0, y1);
      }
      // PV: O^T[d][q] += V^T[d][s] * P^T[s][q], two d-tiles
#pragma unroll
      for (int ks = 0; ks < 4; ++ks) {
        const bf16x8 vfA = *reinterpret_cast<const bf16x8*>(Vc + rA * 128 + ((ks * 32 + hi * 16) ^ swA));
        oA = __builtin_amdgcn_mfma_f32_32x32x16_bf16(vfA, pfs[ks], oA, 0, 0, 0);
        const bf16x8 vfB = *reinterpret_cast<const bf16x8*>(Vc + rB * 128 + ((ks * 32 + hi * 16) ^ swB));
        oB = __builtin_amdgcn_mfma_f32_32x32x16_bf16(vfB, pfs[ks], oB, 0, 0, 0);
      }
    }
    __syncthreads();
    cur ^= 1;
  }
  const float inv = 1.0f / lrun;
  // store: d = 32*dt + 8*E + 4*hi + j, q = qs + l31
  unsigned short* Yp = Y + ((size_t)(b * T_) + q) * (NH * HD) + h * HD + 4 * hi;
#pragma unroll
  for (int E = 0; E < 4; ++E) {
    ushort4 w;
    w.x = f2bf(oA[4 * E + 0] * inv); w.y = f2bf(oA[4 * E + 1] * inv);
    w.z = f2bf(oA[4 * E + 2] * inv); w.w = f2bf(oA[4 * E + 3] * inv);
    *reinterpret_cast<ushort4*>(Yp + E * 8) = w;
    ushort4 v;
    v.x = f2bf(oB[4 * E + 0] * inv); v.y = f2bf(oB[4 * E + 1] * inv);
    v.z = f2bf(oB[4 * E + 2] * inv); v.w = f2bf(oB[4 * E + 3] * inv);
    *reinterpret_cast<ushort4*>(Yp + 32 + E * 8) = v;
  }
}

extern "C" void kernel_launch(void* const* d_in, const int* in_sizes, int n_in,
                              void* d_out, int out_size, void* d_ws, size_t ws_size,
                              hipStream_t stream) {
  const float* x    = (const float*)d_in[0];
  const float* ve   = (const float*)d_in[1];
  const float* cosb = (const float*)d_in[2];
  const float* sinb = (const float*)d_in[3];
  const float* Wq   = (const float*)d_in[4];
  const float* Wk   = (const float*)d_in[5];
  const float* Wv   = (const float*)d_in[6];
  const float* Wo   = (const float*)d_in[7];
  const float* Wg   = (const float*)d_in[8];
  const int*   wlp  = (const int*)d_in[9];

  char* ws = (char*)d_ws;
  unsigned short* xb    = (unsigned short*)ws; ws += (size_t)4096 * 1024 * 2;
  unsigned short* wqkvb = (unsigned short*)ws; ws += (size_t)1536 * 1024 * 2;
  unsigned short* wob   = (unsigned short*)ws; ws += (size_t)1024 * 1024 * 2;
  float*          qkv   = (float*)ws;          ws += (size_t)4096 * 1536 * 4;
  unsigned short* Qn    = (unsigned short*)ws; ws += (size_t)B_ * NH * T_ * HD * 2;
  unsigned short* Kn    = (unsigned short*)ws; ws += (size_t)B_ * NKV * T_ * HD * 2;
  unsigned short* Vt    = (unsigned short*)ws; ws += (size_t)B_ * NKV * HD * T_ * 2;
  unsigned short* yb    = (unsigned short*)ws; ws += (size_t)4096 * 1024 * 2;

  conv_all<<<dim3(2048), dim3(256), 0, stream>>>(x, Wq, Wk, Wv, Wo, xb, wqkvb, wob);

  gemm_bt<<<dim3(NQKV / BN, 4096 / BM), dim3(256), 0, stream>>>(xb, wqkvb, qkv, 4096, NQKV, 1024);

  postproc<<<dim3(4096), dim3(256), 0, stream>>>(qkv, x, ve, cosb, sinb, Wg, Qn, Kn, Vt);

  attn_fwd<<<dim3(32, NH, B_), dim3(128), 0, stream>>>(Qn, Kn, Vt, yb, wlp);

  gemm_bt<<<dim3(1024 / BN, 4096 / BM), dim3(256), 0, stream>>>(yb, wob, (float*)d_out, 4096, 1024, 1024);
}